// Round 6
// baseline (289.943 us; speedup 1.0000x reference)
//
#include <hip/hip_runtime.h>
#include <hip/hip_bf16.h>

typedef short short8 __attribute__((ext_vector_type(8)));
typedef float f32x4 __attribute__((ext_vector_type(4)));
typedef unsigned short u16;
typedef u16 u16x8 __attribute__((ext_vector_type(8)));

static constexpr float kAlpha = 0.2f;

static __device__ inline u16 f2bf(float f) {
  __hip_bfloat16 h = __float2bfloat16(f);
  return *reinterpret_cast<u16*>(&h);
}
static __device__ inline float bf2f(u16 v) {
  unsigned int u = ((unsigned int)v) << 16;
  return __uint_as_float(u);
}

// ---------------- K1: hbT[b][o][n] = (X @ W)[b][n][o]  (bf16) ----------------
__global__ __launch_bounds__(256) void k1_hW(const float* __restrict__ X,
                                             const float* __restrict__ W,
                                             u16* __restrict__ hbT) {
  int row0 = blockIdx.x * 8;  // global row index over b*4096+n
  int o = threadIdx.x & 127;
  int g = threadIdx.x >> 7;   // 0..1
  __shared__ float Xs[8][128];
#pragma unroll
  for (int s = 0; s < 4; ++s) {
    int idx = threadIdx.x + s * 256;
    Xs[idx >> 7][idx & 127] = X[(size_t)row0 * 128 + idx];
  }
  __syncthreads();
  float acc[4] = {0.f, 0.f, 0.f, 0.f};
  for (int k = 0; k < 128; ++k) {
    float w = W[k * 128 + o];
#pragma unroll
    for (int s = 0; s < 4; ++s) acc[s] += Xs[g + 2 * s][k] * w;
  }
  int b = row0 >> 12;
  int n0 = row0 & 4095;
#pragma unroll
  for (int s = 0; s < 4; ++s)
    hbT[((size_t)b * 128 + o) * 4096 + n0 + g + 2 * s] = f2bf(acc[s]);
}

// ---------------- K1b: f1[b][n] = h.a1, f2[b][n] = h.a2 ----------------
__global__ __launch_bounds__(256) void k1b_f(const u16* __restrict__ hbT,
                                             const float* __restrict__ a1,
                                             const float* __restrict__ a2,
                                             float* __restrict__ f1,
                                             float* __restrict__ f2) {
  int idx = blockIdx.x * 256 + threadIdx.x;  // b*4096+n
  int b = idx >> 12;
  int n = idx & 4095;
  const u16* base = hbT + (size_t)b * 128 * 4096 + n;
  float s1 = 0.f, s2 = 0.f;
  for (int o = 0; o < 128; ++o) {
    float h = bf2f(base[(size_t)o * 4096]);
    s1 += h * a1[o];
    s2 += h * a2[o];
  }
  f1[idx] = s1;
  f2[idx] = s2;
}

// ---------------- K2: partial column sums of exp(adj*e), float4 ----------------
// grid = 4b * 16jt * 32ic = 2048 blocks x 256 thr
__global__ __launch_bounds__(256) void k2_dpart(const float* __restrict__ adj,
                                                const float* __restrict__ f1,
                                                const float* __restrict__ f2,
                                                float* __restrict__ dpart) {
  int bid = blockIdx.x;
  int ic = bid & 31;
  int jt = (bid >> 5) & 15;
  int b = bid >> 9;
  int t = threadIdx.x;
  int c = t & 63, r = t >> 6;
  int j = jt * 256 + c * 4;
  const size_t badj = (size_t)b * 4096 * 4096;
  f32x4 f2v = *reinterpret_cast<const f32x4*>(&f2[b * 4096 + j]);
  const float* f1p = f1 + b * 4096;
  int row0 = ic * 128 + r;
  f32x4 sum = (f32x4){0.f, 0.f, 0.f, 0.f};
#pragma unroll 8
  for (int s = 0; s < 32; ++s) {
    int row = row0 + 4 * s;
    f32x4 a = *reinterpret_cast<const f32x4*>(&adj[badj + (size_t)row * 4096 + j]);
    float f1r = f1p[row];
#pragma unroll
    for (int k = 0; k < 4; ++k) {
      float e = f1r + f2v[k];
      e = e >= 0.f ? e : kAlpha * e;
      sum[k] += __expf(a[k] * e);
    }
  }
  __shared__ f32x4 red[256];
  red[t] = sum;
  __syncthreads();
  if (t < 64) {
    f32x4 tt = red[t] + red[t + 64] + red[t + 128] + red[t + 192];
    *reinterpret_cast<f32x4*>(&dpart[(size_t)(b * 32 + ic) * 4096 + j]) = tt;
  }
}

// -------- K2b: rd=1/sum; hs[b][o][j] = hbT[b][o][j] * rd[b][j] (bf16) --------
__global__ __launch_bounds__(256) void k2b_scale(const float* __restrict__ dpart,
                                                 const u16* __restrict__ hbT,
                                                 u16* __restrict__ hs) {
  int idx = blockIdx.x * 256 + threadIdx.x;  // 16384 = b*4096+j
  int b = idx >> 12, j = idx & 4095;
  float s = 0.f;
#pragma unroll
  for (int ic = 0; ic < 32; ++ic) s += dpart[(size_t)(b * 32 + ic) * 4096 + j];
  float rd = 1.0f / s;
  const u16* src = hbT + (size_t)b * 128 * 4096 + j;
  u16* dst = hs + (size_t)b * 128 * 4096 + j;
#pragma unroll 4
  for (int o = 0; o < 128; ++o) {
    dst[(size_t)o * 4096] = f2bf(bf2f(src[(size_t)o * 4096]) * rd);
  }
}

// ---------------- K3: out = P @ hs + bias + input (MFMA bf16) ----------------
// grid 256 blocks (b x 64 row-tiles of 64), 512 thr = 8 waves.
// ZERO LDS, ZERO barriers: A and B fragments loaded direct global->VGPR in
// MFMA fragment layout; exp computed in-register; waves free-run; 2-deep
// static register pipeline covers latency.
__global__ __launch_bounds__(512, 2) void k3_out(
    const float* __restrict__ adj, const u16* __restrict__ hs,
    const float* __restrict__ f1, const float* __restrict__ f2,
    const float* __restrict__ bias, const float* __restrict__ input,
    float* __restrict__ out) {
  int bid = blockIdx.x;
  int b = bid >> 6;
  int i0 = (bid & 63) * 64;
  int t = threadIdx.x;
  int lane = t & 63;
  int w = t >> 6;

  int rg = w & 3;   // row group (16 rows of i)
  int ch = w >> 2;  // column half of o (64)

  const size_t badj = (size_t)b * 4096 * 4096;
  const u16* hb = hs + (size_t)b * 128 * 4096;

  int l15 = lane & 15;
  int l8 = (lane >> 4) * 8;  // k-offset within fragment

  // Per-lane base pointers (fragment layout baked in).
  const float* aptr = adj + badj + (size_t)(i0 + 16 * rg + l15) * 4096 + l8;
  const float* fptr = f2 + b * 4096 + l8;
  const u16* hp0 = hb + (size_t)(64 * ch + 0 * 16 + l15) * 4096 + l8;
  const u16* hp1 = hb + (size_t)(64 * ch + 1 * 16 + l15) * 4096 + l8;
  const u16* hp2 = hb + (size_t)(64 * ch + 2 * 16 + l15) * 4096 + l8;
  const u16* hp3 = hb + (size_t)(64 * ch + 3 * 16 + l15) * 4096 + l8;

  float f1v = f1[b * 4096 + i0 + 16 * rg + l15];

  f32x4 acc[4];
#pragma unroll
  for (int n = 0; n < 4; ++n) acc[n] = (f32x4){0.f, 0.f, 0.f, 0.f};

  // 2-deep pipeline register sets (static names only).
  f32x4 raA0, raA1, raA2, raA3, raB0, raB1, raB2, raB3;
  u16x8 rbA0, rbA1, rbA2, rbA3, rbA4, rbA5, rbA6, rbA7;
  u16x8 rbB0, rbB1, rbB2, rbB3, rbB4, rbB5, rbB6, rbB7;

#define PF(S, J0)                                                  \
  {                                                                \
    int jj = (J0) & 4095; /* tail wraps to valid memory, unused */ \
    ra##S##0 = *reinterpret_cast<const f32x4*>(aptr + jj);         \
    ra##S##1 = *reinterpret_cast<const f32x4*>(aptr + jj + 4);     \
    ra##S##2 = *reinterpret_cast<const f32x4*>(aptr + jj + 32);    \
    ra##S##3 = *reinterpret_cast<const f32x4*>(aptr + jj + 36);    \
    rb##S##0 = *reinterpret_cast<const u16x8*>(hp0 + jj);          \
    rb##S##1 = *reinterpret_cast<const u16x8*>(hp1 + jj);          \
    rb##S##2 = *reinterpret_cast<const u16x8*>(hp2 + jj);          \
    rb##S##3 = *reinterpret_cast<const u16x8*>(hp3 + jj);          \
    rb##S##4 = *reinterpret_cast<const u16x8*>(hp0 + jj + 32);     \
    rb##S##5 = *reinterpret_cast<const u16x8*>(hp1 + jj + 32);     \
    rb##S##6 = *reinterpret_cast<const u16x8*>(hp2 + jj + 32);     \
    rb##S##7 = *reinterpret_cast<const u16x8*>(hp3 + jj + 32);     \
  }

#define COMPUTE(S, J0)                                                             \
  {                                                                                \
    int jj = (J0) & 4095;                                                          \
    f32x4 g0 = *reinterpret_cast<const f32x4*>(fptr + jj);                         \
    f32x4 g1 = *reinterpret_cast<const f32x4*>(fptr + jj + 4);                     \
    f32x4 g2 = *reinterpret_cast<const f32x4*>(fptr + jj + 32);                    \
    f32x4 g3 = *reinterpret_cast<const f32x4*>(fptr + jj + 36);                    \
    u16x8 af;                                                                      \
    _Pragma("unroll") for (int k = 0; k < 4; ++k) {                                \
      float e = f1v + g0[k];                                                       \
      e = e >= 0.f ? e : kAlpha * e;                                               \
      af[k] = f2bf(__expf(ra##S##0[k] * e));                                       \
    }                                                                              \
    _Pragma("unroll") for (int k = 0; k < 4; ++k) {                                \
      float e = f1v + g1[k];                                                       \
      e = e >= 0.f ? e : kAlpha * e;                                               \
      af[4 + k] = f2bf(__expf(ra##S##1[k] * e));                                   \
    }                                                                              \
    acc[0] = __builtin_amdgcn_mfma_f32_16x16x32_bf16(                              \
        *reinterpret_cast<short8*>(&af), *reinterpret_cast<short8*>(&rb##S##0),    \
        acc[0], 0, 0, 0);                                                          \
    acc[1] = __builtin_amdgcn_mfma_f32_16x16x32_bf16(                              \
        *reinterpret_cast<short8*>(&af), *reinterpret_cast<short8*>(&rb##S##1),    \
        acc[1], 0, 0, 0);                                                          \
    acc[2] = __builtin_amdgcn_mfma_f32_16x16x32_bf16(                              \
        *reinterpret_cast<short8*>(&af), *reinterpret_cast<short8*>(&rb##S##2),    \
        acc[2], 0, 0, 0);                                                          \
    acc[3] = __builtin_amdgcn_mfma_f32_16x16x32_bf16(                              \
        *reinterpret_cast<short8*>(&af), *reinterpret_cast<short8*>(&rb##S##3),    \
        acc[3], 0, 0, 0);                                                          \
    _Pragma("unroll") for (int k = 0; k < 4; ++k) {                                \
      float e = f1v + g2[k];                                                       \
      e = e >= 0.f ? e : kAlpha * e;                                               \
      af[k] = f2bf(__expf(ra##S##2[k] * e));                                       \
    }                                                                              \
    _Pragma("unroll") for (int k = 0; k < 4; ++k) {                                \
      float e = f1v + g3[k];                                                       \
      e = e >= 0.f ? e : kAlpha * e;                                               \
      af[4 + k] = f2bf(__expf(ra##S##3[k] * e));                                   \
    }                                                                              \
    acc[0] = __builtin_amdgcn_mfma_f32_16x16x32_bf16(                              \
        *reinterpret_cast<short8*>(&af), *reinterpret_cast<short8*>(&rb##S##4),    \
        acc[0], 0, 0, 0);                                                          \
    acc[1] = __builtin_amdgcn_mfma_f32_16x16x32_bf16(                              \
        *reinterpret_cast<short8*>(&af), *reinterpret_cast<short8*>(&rb##S##5),    \
        acc[1], 0, 0, 0);                                                          \
    acc[2] = __builtin_amdgcn_mfma_f32_16x16x32_bf16(                              \
        *reinterpret_cast<short8*>(&af), *reinterpret_cast<short8*>(&rb##S##6),    \
        acc[2], 0, 0, 0);                                                          \
    acc[3] = __builtin_amdgcn_mfma_f32_16x16x32_bf16(                              \
        *reinterpret_cast<short8*>(&af), *reinterpret_cast<short8*>(&rb##S##7),    \
        acc[3], 0, 0, 0);                                                          \
  }

  PF(A, 0);
  PF(B, 64);
  for (int j0 = 0; j0 < 4096; j0 += 128) {
    COMPUTE(A, j0);
    PF(A, j0 + 128);
    COMPUTE(B, j0 + 64);
    PF(B, j0 + 192);
  }

  // ---- epilogue: + bias + input ----
  int colbase = ch * 64 + l15;
  int rowbase = i0 + rg * 16 + (lane >> 4) * 4;
#pragma unroll
  for (int n = 0; n < 4; ++n) {
    int o = colbase + n * 16;
#pragma unroll
    for (int q = 0; q < 4; ++q) {
      int i = rowbase + q;
      size_t oidx = ((size_t)b * 4096 + i) * 128 + o;
      out[oidx] = acc[n][q] + bias[i * 128 + o] + input[oidx];
    }
  }
}

extern "C" void kernel_launch(void* const* d_in, const int* in_sizes, int n_in,
                              void* d_out, int out_size, void* d_ws, size_t ws_size,
                              hipStream_t stream) {
  const float* input = (const float*)d_in[0];
  const float* adj = (const float*)d_in[1];
  const float* W = (const float*)d_in[2];
  const float* a1 = (const float*)d_in[3];
  const float* a2 = (const float*)d_in[4];
  const float* bias = (const float*)d_in[5];
  float* out = (float*)d_out;

  char* ws = (char*)d_ws;
  u16* hbT = (u16*)(ws);                  // 4*128*4096*2 = 4,194,304 B
  float* f1 = (float*)(ws + 4194304);     // 65,536 B
  float* f2 = (float*)(ws + 4259840);     // 65,536 B
  float* dpart = (float*)(ws + 4325376);  // 4*32*4096*4 = 2,097,152 B
  u16* hs = (u16*)(ws + 6422528);         // 4,194,304 B

  k1_hW<<<2048, 256, 0, stream>>>(input, W, hbT);
  k1b_f<<<64, 256, 0, stream>>>(hbT, a1, a2, f1, f2);
  k2_dpart<<<2048, 256, 0, stream>>>(adj, f1, f2, dpart);
  k2b_scale<<<64, 256, 0, stream>>>(dpart, hbT, hs);
  k3_out<<<256, 512, 0, stream>>>(adj, hs, f1, f2, bias, input, out);
}

// Round 7
// 144.056 us; speedup vs baseline: 2.0127x; 2.0127x over previous
//
#include <hip/hip_runtime.h>
#include <hip/hip_bf16.h>

typedef short short8 __attribute__((ext_vector_type(8)));
typedef float f32x4 __attribute__((ext_vector_type(4)));
typedef unsigned short u16;
typedef u16 u16x4 __attribute__((ext_vector_type(4)));
typedef u16 u16x8 __attribute__((ext_vector_type(8)));

static constexpr float kAlpha = 0.2f;

static __device__ inline u16 f2bf(float f) {
  __hip_bfloat16 h = __float2bfloat16(f);
  return *reinterpret_cast<u16*>(&h);
}
static __device__ inline float bf2f(u16 v) {
  unsigned int u = ((unsigned int)v) << 16;
  return __uint_as_float(u);
}

// ---------------- K1: hbT[b][o][n] = (X @ W)[b][n][o]  (bf16) ----------------
__global__ __launch_bounds__(256) void k1_hW(const float* __restrict__ X,
                                             const float* __restrict__ W,
                                             u16* __restrict__ hbT) {
  int row0 = blockIdx.x * 8;  // global row index over b*4096+n
  int o = threadIdx.x & 127;
  int g = threadIdx.x >> 7;   // 0..1
  __shared__ float Xs[8][128];
#pragma unroll
  for (int s = 0; s < 4; ++s) {
    int idx = threadIdx.x + s * 256;
    Xs[idx >> 7][idx & 127] = X[(size_t)row0 * 128 + idx];
  }
  __syncthreads();
  float acc[4] = {0.f, 0.f, 0.f, 0.f};
  for (int k = 0; k < 128; ++k) {
    float w = W[k * 128 + o];
#pragma unroll
    for (int s = 0; s < 4; ++s) acc[s] += Xs[g + 2 * s][k] * w;
  }
  int b = row0 >> 12;
  int n0 = row0 & 4095;
#pragma unroll
  for (int s = 0; s < 4; ++s)
    hbT[((size_t)b * 128 + o) * 4096 + n0 + g + 2 * s] = f2bf(acc[s]);
}

// ---------------- K1b: f1[b][n] = h.a1, f2[b][n] = h.a2 ----------------
__global__ __launch_bounds__(256) void k1b_f(const u16* __restrict__ hbT,
                                             const float* __restrict__ a1,
                                             const float* __restrict__ a2,
                                             float* __restrict__ f1,
                                             float* __restrict__ f2) {
  int idx = blockIdx.x * 256 + threadIdx.x;  // b*4096+n
  int b = idx >> 12;
  int n = idx & 4095;
  const u16* base = hbT + (size_t)b * 128 * 4096 + n;
  float s1 = 0.f, s2 = 0.f;
  for (int o = 0; o < 128; ++o) {
    float h = bf2f(base[(size_t)o * 4096]);
    s1 += h * a1[o];
    s2 += h * a2[o];
  }
  f1[idx] = s1;
  f2[idx] = s2;
}

// ---------------- K2: partial column sums of exp(adj*e), float4 ----------------
// grid = 4b * 16jt * 32ic = 2048 blocks x 256 thr
__global__ __launch_bounds__(256) void k2_dpart(const float* __restrict__ adj,
                                                const float* __restrict__ f1,
                                                const float* __restrict__ f2,
                                                float* __restrict__ dpart) {
  int bid = blockIdx.x;
  int ic = bid & 31;
  int jt = (bid >> 5) & 15;
  int b = bid >> 9;
  int t = threadIdx.x;
  int c = t & 63, r = t >> 6;
  int j = jt * 256 + c * 4;
  const size_t badj = (size_t)b * 4096 * 4096;
  f32x4 f2v = *reinterpret_cast<const f32x4*>(&f2[b * 4096 + j]);
  const float* f1p = f1 + b * 4096;
  int row0 = ic * 128 + r;
  f32x4 sum = (f32x4){0.f, 0.f, 0.f, 0.f};
#pragma unroll 8
  for (int s = 0; s < 32; ++s) {
    int row = row0 + 4 * s;
    f32x4 a = *reinterpret_cast<const f32x4*>(&adj[badj + (size_t)row * 4096 + j]);
    float f1r = f1p[row];
#pragma unroll
    for (int k = 0; k < 4; ++k) {
      float e = f1r + f2v[k];
      e = e >= 0.f ? e : kAlpha * e;
      sum[k] += __expf(a[k] * e);
    }
  }
  __shared__ f32x4 red[256];
  red[t] = sum;
  __syncthreads();
  if (t < 64) {
    f32x4 tt = red[t] + red[t + 64] + red[t + 128] + red[t + 192];
    *reinterpret_cast<f32x4*>(&dpart[(size_t)(b * 32 + ic) * 4096 + j]) = tt;
  }
}

// -------- K2b: rd=1/sum; hs[b][o][j] = hbT[b][o][j] * rd[b][j] (bf16) --------
// grid = 4b * 16jb * 8og = 512 blocks x 256 thr (o-split for full-chip spread)
__global__ __launch_bounds__(256) void k2b_scale(const float* __restrict__ dpart,
                                                 const u16* __restrict__ hbT,
                                                 u16* __restrict__ hs) {
  int bid = blockIdx.x;
  int og = bid & 7;
  int jb = (bid >> 3) & 15;
  int b = bid >> 7;
  int j = jb * 256 + threadIdx.x;
  float s = 0.f;
#pragma unroll
  for (int ic = 0; ic < 32; ++ic) s += dpart[(size_t)(b * 32 + ic) * 4096 + j];
  float rd = 1.0f / s;
  const u16* src = hbT + (size_t)b * 128 * 4096 + j;
  u16* dst = hs + (size_t)b * 128 * 4096 + j;
#pragma unroll 4
  for (int o = og * 16; o < og * 16 + 16; ++o) {
    dst[(size_t)o * 4096] = f2bf(bf2f(src[(size_t)o * 4096]) * rd);
  }
}

// ---------------- K3: out = P @ hs + bias + input (MFMA bf16) ----------------
// grid 512 blocks (4b x 128 row-tiles of 32) -> 2 blocks/CU, 512 thr = 8 waves.
// XCD-swizzled blockIdx. Double-buffered LDS (45KB), 4-deep register prefetch
// (adj + f2 + hs), lgkmcnt-only barriers (global loads stay in flight).
#define LROW 72
#define BARRIER()                                      \
  {                                                    \
    asm volatile("s_waitcnt lgkmcnt(0)" ::: "memory"); \
    __builtin_amdgcn_s_barrier();                      \
  }
__global__ __launch_bounds__(512, 4) void k3_out(
    const float* __restrict__ adj, const u16* __restrict__ hs,
    const float* __restrict__ f1, const float* __restrict__ f2,
    const float* __restrict__ bias, const float* __restrict__ input,
    float* __restrict__ out) {
  int bid0 = blockIdx.x;
  int bid = ((bid0 & 7) << 6) | (bid0 >> 3);  // XCD swizzle (512 % 8 == 0)
  int b = bid >> 7;
  int i0 = (bid & 127) * 32;
  int t = threadIdx.x;
  int lane = t & 63;
  int w = t >> 6;

  __shared__ u16 As[2][32 * LROW];   // P tile [i][j]   (9.2 KB)
  __shared__ u16 Bs[2][128 * LROW];  // hs tile [o][j]  (36.9 KB)

  const size_t badj = (size_t)b * 4096 * 4096;
  const u16* hb = hs + (size_t)b * 128 * 4096;
  const float* f2b = f2 + b * 4096;

  // A staging map: thread covers row rr, cols c0..c0+3 of the 32x64 adj tile
  int rr = t >> 4;         // 0..31
  int c0 = (t & 15) * 4;   // 0..60
  // B staging map: thread covers o=bo, 16 cols starting bc0
  int bo = t >> 2;         // 0..127
  int bc0 = (t & 3) * 16;  // 0..48

  float f1v = f1[b * 4096 + i0 + rr];

  int rg = w & 1;   // row group (16 rows of i)
  int ch = w >> 1;  // o quarter (32 cols)
  int l15 = lane & 15;
  int l8 = (lane >> 4) * 8;

  f32x4 acc[2];
#pragma unroll
  for (int n = 0; n < 2; ++n) acc[n] = (f32x4){0.f, 0.f, 0.f, 0.f};

  // 4 named prefetch register sets (static indexing only)
  f32x4 raA, raB, raC, raD;      // adj
  f32x4 rfA, rfB, rfC, rfD;      // f2
  u16x8 rbA0, rbA1, rbB0, rbB1, rbC0, rbC1, rbD0, rbD1;  // hs

#define PREFETCH(S, J0)                                                    \
  {                                                                        \
    int jj = (J0) & 4095; /* tail prefetches wrap, values unused */        \
    ra##S = *reinterpret_cast<const f32x4*>(                               \
        adj + badj + (size_t)(i0 + rr) * 4096 + jj + c0);                  \
    rf##S = *reinterpret_cast<const f32x4*>(f2b + jj + c0);                \
    const u16x8* bp =                                                      \
        reinterpret_cast<const u16x8*>(hb + (size_t)bo * 4096 + jj + bc0); \
    rb##S##0 = bp[0];                                                      \
    rb##S##1 = bp[1];                                                      \
  }

#define STORE(S, BUF)                                                    \
  {                                                                      \
    u16x4 pv;                                                            \
    _Pragma("unroll") for (int k = 0; k < 4; ++k) {                      \
      float e = f1v + rf##S[k];                                          \
      e = e >= 0.f ? e : kAlpha * e;                                     \
      pv[k] = f2bf(__expf(ra##S[k] * e));                                \
    }                                                                    \
    *reinterpret_cast<u16x4*>(&As[BUF][rr * LROW + c0]) = pv;            \
    *reinterpret_cast<u16x8*>(&Bs[BUF][bo * LROW + bc0]) = rb##S##0;     \
    *reinterpret_cast<u16x8*>(&Bs[BUF][bo * LROW + bc0 + 8]) = rb##S##1; \
  }

#define DOMFMA(BUF)                                                                \
  {                                                                                \
    _Pragma("unroll") for (int kk = 0; kk < 64; kk += 32) {                        \
      short8 af = *reinterpret_cast<const short8*>(                                \
          &As[BUF][(16 * rg + l15) * LROW + kk + l8]);                             \
      _Pragma("unroll") for (int n = 0; n < 2; ++n) {                              \
        short8 bf = *reinterpret_cast<const short8*>(                              \
            &Bs[BUF][(32 * ch + n * 16 + l15) * LROW + kk + l8]);                  \
        acc[n] = __builtin_amdgcn_mfma_f32_16x16x32_bf16(af, bf, acc[n], 0, 0, 0); \
      }                                                                            \
    }                                                                              \
  }

  // Prologue: fill the 4-deep pipeline.
  PREFETCH(A, 0);
  PREFETCH(B, 64);
  PREFETCH(C, 128);
  PREFETCH(D, 192);

  for (int j0 = 0; j0 < 4096; j0 += 256) {
    STORE(A, 0);
    BARRIER();
    DOMFMA(0);
    PREFETCH(A, j0 + 256);
    STORE(B, 1);
    BARRIER();
    DOMFMA(1);
    PREFETCH(B, j0 + 320);
    STORE(C, 0);
    BARRIER();
    DOMFMA(0);
    PREFETCH(C, j0 + 384);
    STORE(D, 1);
    BARRIER();
    DOMFMA(1);
    PREFETCH(D, j0 + 448);
  }

  // ---- epilogue: + bias + input ----
  int colbase = 32 * ch + l15;
  int rowbase = i0 + rg * 16 + (lane >> 4) * 4;
#pragma unroll
  for (int n = 0; n < 2; ++n) {
    int o = colbase + n * 16;
#pragma unroll
    for (int q = 0; q < 4; ++q) {
      int i = rowbase + q;
      size_t oidx = ((size_t)b * 4096 + i) * 128 + o;
      out[oidx] = acc[n][q] + bias[i * 128 + o] + input[oidx];
    }
  }
}

extern "C" void kernel_launch(void* const* d_in, const int* in_sizes, int n_in,
                              void* d_out, int out_size, void* d_ws, size_t ws_size,
                              hipStream_t stream) {
  const float* input = (const float*)d_in[0];
  const float* adj = (const float*)d_in[1];
  const float* W = (const float*)d_in[2];
  const float* a1 = (const float*)d_in[3];
  const float* a2 = (const float*)d_in[4];
  const float* bias = (const float*)d_in[5];
  float* out = (float*)d_out;

  char* ws = (char*)d_ws;
  u16* hbT = (u16*)(ws);                  // 4*128*4096*2 = 4,194,304 B
  float* f1 = (float*)(ws + 4194304);     // 65,536 B
  float* f2 = (float*)(ws + 4259840);     // 65,536 B
  float* dpart = (float*)(ws + 4325376);  // 4*32*4096*4 = 2,097,152 B
  u16* hs = (u16*)(ws + 6422528);         // 4,194,304 B

  k1_hW<<<2048, 256, 0, stream>>>(input, W, hbT);
  k1b_f<<<64, 256, 0, stream>>>(hbT, a1, a2, f1, f2);
  k2_dpart<<<2048, 256, 0, stream>>>(adj, f1, f2, dpart);
  k2b_scale<<<512, 256, 0, stream>>>(dpart, hbT, hs);
  k3_out<<<512, 512, 0, stream>>>(adj, hs, f1, f2, bias, input, out);
}